// Round 13
// baseline (61.111 us; speedup 1.0000x reference)
//
#include <hip/hip_runtime.h>
#include <math.h>

// DCNv2 forward: B=4, Cin=Cout=64, H=W=128, 3x3, stride=1, pad=1, dil=1, groups=dg=1
#define H_    128
#define W_    128
#define HW_   (H_ * W_)
#define CIN_  64
#define COUT_ 64
#define K2_   9
#define B_    4
#define NROWS 10
#define LDS_BYTES (NROWS * 128 * 64)   // 10 rows x 128 px x 4 chunks x 16B = 81920 (80 KiB)

typedef __bf16 bf16x8 __attribute__((ext_vector_type(8)));
typedef __bf16 bf16x4 __attribute__((ext_vector_type(4)));
typedef float  f32x4  __attribute__((ext_vector_type(4)));

// weight [Cout][Cin][3][3] -> lane-linear MFMA A-frag layout:
// wt3[k][s][ct][lane][e] = weight[ct*16+(lane&15)][s*32+(lane>>4)*8+e][k]
__global__ __launch_bounds__(256) void wtrans3_kernel(const float* __restrict__ w,
                                                      __bf16* __restrict__ wt3) {
    int idx = blockIdx.x * 256 + threadIdx.x;     // 9*2*4*64*8 = 36864
    if (idx >= K2_ * 2 * 4 * 64 * 8) return;
    int e    = idx & 7;
    int lane = (idx >> 3) & 63;
    int ct   = (idx >> 9) & 3;
    int s    = (idx >> 11) & 1;
    int k    = idx >> 12;
    int co   = ct * 16 + (lane & 15);
    int cin  = s * 32 + (lane >> 4) * 8 + e;
    wt3[idx] = (__bf16)w[(co * CIN_ + cin) * K2_ + k];
}

// cin-split DCNv2: one block = 2 output rows x ONE 32-channel cin half.
// 512 blocks (256 row-pairs x 2 halves), 1024 thr, 80 KiB LDS -> 2 blocks/CU,
// 8 waves/SIMD. Each block computes a partial K-sum; halves combine via
// device-scope atomicAdd into a zero-initialized output (half 0 adds bias).
// LDS: [row][px] records of 4 chunks x 16B, slot q = (chunk + px + (px>>3)) & 3.
__global__ __launch_bounds__(1024, 8) void dcn_half_kernel(
    const float* __restrict__ x,       // [B, Cin, H, W] fp32
    const float* __restrict__ offset,  // [B, 18, H, W]
    const float* __restrict__ mask,    // [B, 9, H, W]
    const __bf16* __restrict__ wt3,    // lane-linear A-frags [k][s][ct][lane][8]
    const float* __restrict__ bias,
    float* __restrict__ out)           // [B, Cout, H, W], pre-zeroed
{
    extern __shared__ char sm[];

    const int tid  = threadIdx.x;
    const int wave = tid >> 6;
    const int lane = tid & 63;
    const int n16  = lane & 15;
    const int kb   = lane >> 4;        // chunk 0..3 within this block's cin half

    const int bid0 = blockIdx.x;                    // 512 blocks
    const int bidx = (bid0 & 7) * 64 + (bid0 >> 3); // bijective XCD swizzle
    const int half = bidx >> 8;                     // cin half 0/1
    const int pair = bidx & 255;
    const int b    = pair >> 6;
    const int ho0  = (pair & 63) * 2;               // base output row (even)

    const float* xh = x + (size_t)b * CIN_ * HW_ + (size_t)(half * 32) * HW_;

    // ---------- stage rows [ho0-4, ho0+5] x 32 ch into swizzled bf16 LDS ----------
    {
        const int px4   = tid & 31;        // 4-px granule
        const int cg    = (tid >> 5) & 7;  // 8 channel groups of 4
        const int rowg  = tid >> 8;        // 0..3
        const int c0    = cg * 4;          // local channel 0..28
        const int chunk = c0 >> 3;         // 0..3
        const int eoff  = (c0 & 7) * 2;    // byte offset within 16B chunk
#pragma unroll
        for (int it = 0; it < 3; ++it) {
            const int r = it * 4 + rowg;               // 0..11, guard <10
            if (r < NROWS) {
                const int srow = min(max(ho0 - 4 + r, 0), H_ - 1);
                const float* g = xh + ((size_t)c0 * H_ + srow) * W_ + px4 * 4;
                const float4 v0 = *(const float4*)(g);
                const float4 v1 = *(const float4*)(g + HW_);
                const float4 v2 = *(const float4*)(g + 2 * HW_);
                const float4 v3 = *(const float4*)(g + 3 * HW_);
                const float* f0 = (const float*)&v0;
                const float* f1 = (const float*)&v1;
                const float* f2 = (const float*)&v2;
                const float* f3 = (const float*)&v3;
#pragma unroll
                for (int e = 0; e < 4; ++e) {
                    const int px = px4 * 4 + e;
                    const int q  = (chunk + px + (px >> 3)) & 3;
                    bf16x4 pk;
                    pk[0] = (__bf16)f0[e];
                    pk[1] = (__bf16)f1[e];
                    pk[2] = (__bf16)f2[e];
                    pk[3] = (__bf16)f3[e];
                    *(bf16x4*)(sm + ((size_t)(r * 128 + px)) * 64 + q * 16 + eoff) = pk;
                }
            }
        }
    }
    __syncthreads();

    // ---------- fused sample + MFMA (partial K-sum over this half) ----------
    const int rr  = wave >> 3;            // which of the 2 output rows
    const int til = wave & 7;             // 16-px tile within the row
    const int ho  = ho0 + rr;
    const int wos = til * 16 + n16;
    const int pix = ho * W_ + wos;
    const float* offb = offset + (size_t)b * (2 * K2_) * HW_ + pix;
    const float* mb   = mask   + (size_t)b * K2_ * HW_ + pix;

    f32x4 acc[4];
#pragma unroll
    for (int t = 0; t < 4; ++t) acc[t] = (f32x4){0.f, 0.f, 0.f, 0.f};

    float oy = offb[0];
    float ox = offb[HW_];
    float mm = mb[0];

#pragma unroll 3
    for (int k = 0; k < K2_; ++k) {
        const int ky = k / 3, kx = k % 3;
        const float py  = (float)(ho - 1 + ky) + oy;
        const float pxf = (float)(wos - 1 + kx) + ox;
        const float fy = floorf(py), fx = floorf(pxf);
        const int   y0 = (int)fy,    x0 = (int)fx;
        const float ly = py - fy,    lx = pxf - fx;

        // weights: validity folded (window handled by frag patching below)
        const float A0 = (y0 >= 0 && y0 < H_)         ? mm * (1.f - ly) : 0.f;
        const float A1 = (y0 + 1 >= 0 && y0 + 1 < H_) ? mm * ly         : 0.f;
        const float vx0 = (x0 >= 0 && x0 < W_)         ? 1.f : 0.f;
        const float vx1 = (x0 + 1 >= 0 && x0 + 1 < W_) ? 1.f : 0.f;
        const float l0x = (1.f - lx) * vx0;
        const float l1x = lx * vx1;
        const float W00 = A0 * l0x, W01 = A0 * l1x;
        const float W10 = A1 * l0x, W11 = A1 * l1x;

        const int cy0 = min(max(y0, 0), H_ - 1);
        const int cy1 = min(max(y0 + 1, 0), H_ - 1);
        const int cx0 = min(max(x0, 0), W_ - 1);
        const int cx1 = min(max(x0 + 1, 0), W_ - 1);

        const int s0 = cy0 - ho0 + 4;               // window slot
        const int s1 = cy1 - ho0 + 4;
        const bool need0 = ((unsigned)s0 > 9u) && (A0 != 0.f);
        const bool need1 = ((unsigned)s1 > 9u) && (A1 != 0.f);
        const int s0c = min(max(s0, 0), 9);
        const int s1c = min(max(s1, 0), 9);

        const int o0 = ((kb + cx0 + (cx0 >> 3)) & 3) << 4;
        const int o1 = ((kb + cx1 + (cx1 >> 3)) & 3) << 4;
        const char* r00 = sm + ((size_t)(s0c * 128 + cx0)) * 64;
        const char* r01 = sm + ((size_t)(s0c * 128 + cx1)) * 64;
        const char* r10 = sm + ((size_t)(s1c * 128 + cx0)) * 64;
        const char* r11 = sm + ((size_t)(s1c * 128 + cx1)) * 64;

        bf16x8 a00 = *(const bf16x8*)(r00 + o0);
        bf16x8 a01 = *(const bf16x8*)(r01 + o1);
        bf16x8 a10 = *(const bf16x8*)(r10 + o0);
        bf16x8 a11 = *(const bf16x8*)(r11 + o1);

        // rare out-of-window fallback (exec-masked)
        if (__builtin_expect(need0, 0)) {
            const float* gl = xh + (size_t)(kb * 8) * HW_ + (size_t)cy0 * W_;
#pragma unroll
            for (int e = 0; e < 8; ++e) {
                a00[e] = (__bf16)gl[(size_t)e * HW_ + cx0];
                a01[e] = (__bf16)gl[(size_t)e * HW_ + cx1];
            }
        }
        if (__builtin_expect(need1, 0)) {
            const float* gl = xh + (size_t)(kb * 8) * HW_ + (size_t)cy1 * W_;
#pragma unroll
            for (int e = 0; e < 8; ++e) {
                a10[e] = (__bf16)gl[(size_t)e * HW_ + cx0];
                a11[e] = (__bf16)gl[(size_t)e * HW_ + cx1];
            }
        }

        if (k + 1 < K2_) {   // prefetch next tap's offsets
            oy = offb[(2 * (k + 1)) * HW_];
            ox = offb[(2 * (k + 1) + 1) * HW_];
            mm = mb[(k + 1) * HW_];
        }

        // ---- VALU blend -> one bf16 B-frag (8 cin of this half) ----
        bf16x8 bf0;
#pragma unroll
        for (int e = 0; e < 8; ++e) {
            const float v = W00 * (float)a00[e] + W01 * (float)a01[e]
                          + W10 * (float)a10[e] + W11 * (float)a11[e];
            bf0[e] = (__bf16)v;
        }

        // ---- 4 MFMAs (one K=32 step per co-tile) ----
        const __bf16* wk = wt3 + (size_t)k * (2 * 4 * 64 * 8) + half * 2048 + lane * 8;
#pragma unroll
        for (int ct = 0; ct < 4; ++ct) {
            const bf16x8 A = *(const bf16x8*)(wk + ct * 512);
            acc[ct] = __builtin_amdgcn_mfma_f32_16x16x32_bf16(A, bf0, acc[ct], 0, 0, 0);
        }
    }

    // ---------- epilogue: atomic combine (half 0 carries the bias) ----------
#pragma unroll
    for (int ct = 0; ct < 4; ++ct) {
#pragma unroll
        for (int r = 0; r < 4; ++r) {
            const int co = ct * 16 + kb * 4 + r;
            const float v = acc[ct][r] + (half == 0 ? bias[co] : 0.f);
            atomicAdd(&out[((size_t)(b * COUT_ + co)) * HW_ + pix], v);
        }
    }
}

extern "C" void kernel_launch(void* const* d_in, const int* in_sizes, int n_in,
                              void* d_out, int out_size, void* d_ws, size_t ws_size,
                              hipStream_t stream) {
    const float* x      = (const float*)d_in[0];
    const float* offset = (const float*)d_in[1];
    const float* mask   = (const float*)d_in[2];
    const float* weight = (const float*)d_in[3];
    const float* bias   = (const float*)d_in[4];
    float* out = (float*)d_out;
    __bf16* wt3 = (__bf16*)d_ws;   // 73728 bytes

    hipFuncSetAttribute(reinterpret_cast<const void*>(dcn_half_kernel),
                        hipFuncAttributeMaxDynamicSharedMemorySize, LDS_BYTES);

    // zero output (atomic accumulation target) — async, graph-safe
    hipMemsetAsync(d_out, 0, (size_t)out_size * sizeof(float), stream);

    wtrans3_kernel<<<(K2_ * 2 * 4 * 64 * 8 + 255) / 256, 256, 0, stream>>>(weight, wt3);
    // 512 blocks x 1024 threads: 2 blocks/CU (one per cin half), 2 output rows each
    dcn_half_kernel<<<B_ * H_, 1024, LDS_BYTES, stream>>>(x, offset, mask, wt3, bias, out);
}